// Round 1
// baseline (353.754 us; speedup 1.0000x reference)
//
#include <hip/hip_runtime.h>
#include <hip/hip_bf16.h>
#include <math.h>

typedef __hip_bfloat16 hbf;
typedef short bf16x8 __attribute__((ext_vector_type(8)));
typedef float f32x4 __attribute__((ext_vector_type(4)));

// ---------------- problem constants ----------------
constexpr int NL  = 4096;
constexpr int HH  = 256;
constexpr int NE  = 8192;
constexpr int DIc = 512;
constexpr int DSc = 8;
constexpr int CLc = 16;    // scan chunk length (256 chunks)
constexpr int NOUT = 12416;

// ---------------- workspace layout (float offsets) ----------------
constexpr size_t O_MBUF  = 0;         // 1048576  gcn msgs; scan P; attn op0/op1(bf16)
constexpr size_t O_QK    = 1048576;   // 1048576  scan Hl (temp)
constexpr size_t O_H2    = 2097152;   // 1048576  h2 fp32 (live to fus resid)
constexpr size_t O_CATB  = 3145728;   // 1572864  catb bf16 [NL][768]
constexpr size_t O_XZB   = 4718592;   // 2097152  xzb bf16 [NL][1024]; op6/op7(bf16) after scan3
constexpr size_t O_XC    = 6815744;   // 2097152  fused fp32 (epilogue region)
constexpr size_t O_DELTA = 8912896;   // 2097152  delta; op2..op5(bf16) after scan3
constexpr size_t O_PROJ  = 11010048;  // 131072   proj fp32
constexpr size_t O_HST   = 11141120;  // 1048576  Hst; lsum after scan3
constexpr size_t O_Y     = 12189696;  // 1048576  yb bf16; aob bf16
constexpr size_t O_POOL  = 13238272;  // 2048
constexpr size_t O_DINV  = 13240320;  // 4096
constexpr size_t O_B768  = 13244416;  // 768
constexpr size_t O_INT   = 13245184;  // 81928 ints
constexpr size_t O_WT    = 13327112;  // 512000
constexpr size_t O_XB    = 13839112;  // 65536
constexpr size_t O_H0B   = 13904648;  // 524288
constexpr size_t O_H2B   = 14428936;  // 524288
constexpr size_t O_XCB   = 14953224;  // 1048576
constexpr size_t O_DTAB  = 16001800;  // 65536
constexpr size_t O_QKB   = 16067584;  // 1048576  qkB bf16 [NL][512]
constexpr size_t O_VTB   = 17116160;  // 524288   vtB bf16 [256][NL]
constexpr size_t O_PART  = 17640448;  // 262144   ln partial pools [128][2048]
constexpr size_t O_HWT   = 17902592;  // 397312   transposed head weights [1552][256]
// total 18299904 floats = 73.2 MB (ws = 256 MB)

// ---------------- weight transpose-cast table (in|q|k|v contiguous) ----------------
constexpr int NW = 12;
__device__ __constant__ int wc_cum[NW+1] = {
    0, 8192, 73728, 139264, 155648, 172032, 303104, 565248,
    630784, 696320, 761856, 827392, 1024000 };
__device__ __constant__ int wc_K [NW] = {32,256,256,512,16,512,256,256,256,256,256,768};
__device__ __constant__ int wc_N [NW] = {256,256,256,32,512,256,1024,256,256,256,256,256};
__device__ __constant__ int wc_Kp[NW] = {32,256,256,512,32,512,256,256,256,256,256,768};
struct WSrc { const float* p[NW]; };
struct HSrc { const float* p[7]; };
struct OPtrs { hbf* p[8]; };

__device__ __constant__ int hw_b[8]  = {0,1,5,8,520,1032,1544,1552};
__device__ __constant__ int hw_nc[7] = {1,4,3,512,512,512,8};

// prep: weight transpose-cast + x cast + b768 + part zero + indeg zero + head-w transpose
constexpr int PR_W = 1024000;
constexpr int PR_X = PR_W + 131072;     // 1155072
constexpr int PR_B = PR_X + 768;        // 1155840
constexpr int PR_P = PR_B + 262144;     // 1417984
constexpr int PR_I = PR_P + 4096;       // 1422080
constexpr int PR_H = PR_I + 397312;     // 1819392
__global__ __launch_bounds__(256) void prep_k(WSrc ws, hbf* __restrict__ wt,
        const float* __restrict__ x, hbf* __restrict__ xb,
        const float* __restrict__ bq, const float* __restrict__ bk,
        const float* __restrict__ bv,
        float* __restrict__ b768, float* __restrict__ part, int* __restrict__ indeg,
        HSrc hs, float* __restrict__ hwt) {
    int idx = blockIdx.x*256 + threadIdx.x;
    if (idx < PR_W) {
        int lo = 0, hi = NW-1;
        while (lo < hi) { int mid = (lo+hi+1)>>1; if (idx >= wc_cum[mid]) lo = mid; else hi = mid-1; }
        int local = idx - wc_cum[lo];
        int Kp = wc_Kp[lo], K = wc_K[lo], N = wc_N[lo];
        int n = local / Kp, k = local - n*Kp;
        float v = (k < K) ? ws.p[lo][(size_t)k*N + n] : 0.0f;
        wt[idx] = __float2bfloat16(v);
    } else if (idx < PR_X) {
        int i = idx - PR_W;
        xb[i] = __float2bfloat16(x[i]);
    } else if (idx < PR_B) {
        int i = idx - PR_X;
        b768[i] = (i < 256) ? bq[i] : (i < 512 ? bk[i-256] : bv[i-512]);
    } else if (idx < PR_P) {
        part[idx - PR_B] = 0.0f;
    } else if (idx < PR_I) {
        indeg[idx - PR_P] = 0;
    } else if (idx < PR_H) {
        int i = idx - PR_I;
        int j = i >> 8, k = i & 255;
        int seg = 0;
        while (j >= hw_b[seg+1]) seg++;
        int col = j - hw_b[seg], nc = hw_nc[seg];
        hwt[(size_t)j*256 + k] = hs.p[seg][(size_t)k*nc + col];
    }
}

// ---------------- graph prep ----------------
__global__ void count_k(const int* __restrict__ ei, int* __restrict__ indeg) {
    int i = blockIdx.x*256 + threadIdx.x;
    int b = i >> 13, e = i & 8191;
    int dst = ei[b*2*NE + NE + e] + (b << 9);
    atomicAdd(&indeg[dst], 1);
}

__global__ __launch_bounds__(1024) void prefix_k(const int* __restrict__ indeg,
                                                 int* __restrict__ row_start,
                                                 int* __restrict__ cursor,
                                                 float* __restrict__ dinv) {
    __shared__ int part[1024];
    int t = threadIdx.x;
    int v0[4]; int s = 0;
    #pragma unroll
    for (int i = 0; i < 4; i++) {
        int cnt = indeg[t*4 + i];
        v0[i] = s; s += cnt;
        dinv[t*4 + i] = rsqrtf(1.0f + (float)cnt);
    }
    part[t] = s;
    __syncthreads();
    for (int o = 1; o < 1024; o <<= 1) {
        int x = (t >= o) ? part[t-o] : 0;
        __syncthreads();
        part[t] += x;
        __syncthreads();
    }
    int base = (t > 0) ? part[t-1] : 0;
    #pragma unroll
    for (int i = 0; i < 4; i++) {
        int rs = base + v0[i];
        row_start[t*4+i] = rs; cursor[t*4+i] = rs;
    }
    if (t == 1023) row_start[4096] = part[1023];
}

__global__ void scatter_k(const int* __restrict__ ei, int* __restrict__ cursor,
                          int* __restrict__ csr) {
    int i = blockIdx.x*256 + threadIdx.x;
    int b = i >> 13, e = i & 8191;
    int src = ei[b*2*NE + e]       + (b << 9);
    int dst = ei[b*2*NE + NE + e]  + (b << 9);
    int pos = atomicAdd(&cursor[dst], 1);
    csr[pos] = src;
}

// gather; MODE 1 adds fp32 out + catb(cols 0..255) write
template<int MODE>
__global__ __launch_bounds__(256) void gather_k(const float* __restrict__ m,
                        const int* __restrict__ csr, const int* __restrict__ row_start,
                        const float* __restrict__ dinv, const float* __restrict__ bias,
                        float* __restrict__ out, hbf* __restrict__ outb,
                        hbf* __restrict__ catb) {
    int n = blockIdx.x, c = threadIdx.x;
    float dn = dinv[n];
    float acc = m[(size_t)n*HH + c] * dn * dn;
    int e0 = row_start[n], e1 = row_start[n+1];
    for (int e = e0; e < e1; e++) {
        int s = csr[e];
        acc += m[(size_t)s*HH + c] * (dinv[s] * dn);
    }
    float r = fmaxf(acc + bias[c], 0.0f);
    if (MODE) {
        out[(size_t)n*HH + c] = r;
        catb[(size_t)n*768 + c] = __float2bfloat16(r);
    }
    outb[(size_t)n*HH + c] = __float2bfloat16(r);
}

// ---------------- bf16 MFMA GEMM: 512 threads / 8 waves, 64x64 tile, BK=64 ----------------
// OUTM: 0 fp32, 1 bf16, 4 proj+dtab, 5 fused in_proj+QKV (xzb | qkB scaled | vtB transposed)
// ACT: 0 none, 1 relu, 2 softplus
template<int ACT, int OUTM>
__global__ __launch_bounds__(512) void mg_k(const unsigned short* __restrict__ A,
        const unsigned short* __restrict__ Bt, const float* __restrict__ bias,
        void* __restrict__ Cp, int ldc, void* __restrict__ Cp2, void* __restrict__ Cp3,
        const float* __restrict__ resid, int ldr, int M, int K, int N)
{
    __shared__ __align__(16) unsigned short Asm[2][64][40];
    __shared__ __align__(16) unsigned short Bsm[2][64][40];
    int t = threadIdx.x;
    int lane = t & 63, w = t >> 6;
    int wm = w & 3, wn = w >> 2;
    int row0 = blockIdx.x * 64, col0 = blockIdx.y * 64;
    int sr = t >> 3;
    int sk8 = (t & 7) * 8;
    int su = sk8 >> 5, so = sk8 & 31;
    f32x4 acc0 = {}, acc1 = {};
    int fr = lane & 15, fq8 = (lane >> 4) * 8;

    uint4 zz = make_uint4(0u,0u,0u,0u);
    uint4 ra = zz, rb = zz;
    bool bnv = (col0 + sr) < N;
    if (sk8 < K) {
        ra = *(const uint4*)&A[(size_t)(row0+sr)*K + sk8];
        if (bnv) rb = *(const uint4*)&Bt[(size_t)(col0+sr)*K + sk8];
    }

    for (int k0 = 0; k0 < K; k0 += 64) {
        __syncthreads();
        *(uint4*)&Asm[su][sr][so] = ra;
        *(uint4*)&Bsm[su][sr][so] = rb;
        __syncthreads();
        int kn = k0 + 64;
        if (kn < K) {
            ra = rb = zz;
            if (kn + sk8 < K) {
                ra = *(const uint4*)&A[(size_t)(row0+sr)*K + kn + sk8];
                if (bnv) rb = *(const uint4*)&Bt[(size_t)(col0+sr)*K + kn + sk8];
            }
        }
        #pragma unroll
        for (int ks = 0; ks < 2; ks++) {
            bf16x8 a  = *(bf16x8*)&Asm[ks][wm*16 + fr][fq8];
            bf16x8 b0 = *(bf16x8*)&Bsm[ks][wn*32 + fr][fq8];
            bf16x8 b1 = *(bf16x8*)&Bsm[ks][wn*32 + 16 + fr][fq8];
            acc0 = __builtin_amdgcn_mfma_f32_16x16x32_bf16(a, b0, acc0, 0, 0, 0);
            acc1 = __builtin_amdgcn_mfma_f32_16x16x32_bf16(a, b1, acc1, 0, 0, 0);
        }
    }

    int fc = lane & 15, frq = (lane >> 4) * 4;
    if constexpr (OUTM == 4) {
        #pragma unroll
        for (int nt = 0; nt < 2; nt++) {
            int col = col0 + wn*32 + nt*16 + fc;
            if (col >= 32) continue;
            f32x4& av = nt ? acc1 : acc0;
            #pragma unroll
            for (int i = 0; i < 4; i++) {
                int row = row0 + wm*16 + frq + i;
                float v = av[i];
                ((float*)Cp)[(size_t)row*32 + col] = v;
                ((hbf*)Cp2)[(size_t)row*32 + col] = __float2bfloat16((col < 16) ? v : 0.0f);
            }
        }
    } else if constexpr (OUTM == 5) {
        if (col0 < 1024) {
            #pragma unroll
            for (int nt = 0; nt < 2; nt++) {
                int col = col0 + wn*32 + nt*16 + fc;
                f32x4& av = nt ? acc1 : acc0;
                #pragma unroll
                for (int i = 0; i < 4; i++) {
                    int row = row0 + wm*16 + frq + i;
                    ((hbf*)Cp)[(size_t)row*1024 + col] = __float2bfloat16(av[i]);
                }
            }
        } else if (col0 < 1536) {
            #pragma unroll
            for (int nt = 0; nt < 2; nt++) {
                int gcol = col0 + wn*32 + nt*16 + fc;
                int col = gcol - 1024;
                float bvv = bias[col];
                float sc = (col < 256) ? 0.125f : 1.0f;
                f32x4& av = nt ? acc1 : acc0;
                #pragma unroll
                for (int i = 0; i < 4; i++) {
                    int row = row0 + wm*16 + frq + i;
                    ((hbf*)Cp2)[(size_t)row*512 + col] = __float2bfloat16((av[i] + bvv) * sc);
                }
            }
        } else {
            __shared__ __align__(16) unsigned short Ts[64][72];
            #pragma unroll
            for (int nt = 0; nt < 2; nt++) {
                int gcol = col0 + wn*32 + nt*16 + fc;
                float bvv = bias[gcol - 1024];
                f32x4& av = nt ? acc1 : acc0;
                #pragma unroll
                for (int i = 0; i < 4; i++)
                    *(hbf*)&Ts[wn*32 + nt*16 + fc][wm*16 + frq + i] = __float2bfloat16(av[i] + bvv);
            }
            __syncthreads();
            int c = t >> 3, rs = (t & 7) * 8;
            *(uint4*)((hbf*)Cp3 + (size_t)(col0 - 1536 + c)*NL + row0 + rs) = *(uint4*)&Ts[c][rs];
        }
    } else {
        #pragma unroll
        for (int nt = 0; nt < 2; nt++) {
            int col = col0 + wn*32 + nt*16 + fc;
            if (col >= N) continue;
            float bvv = bias ? bias[col] : 0.0f;
            f32x4& av = nt ? acc1 : acc0;
            #pragma unroll
            for (int i = 0; i < 4; i++) {
                int row = row0 + wm*16 + frq + i;
                float v = av[i] + bvv;
                if (ACT == 1) v = fmaxf(v, 0.0f);
                if (ACT == 2) v = (v > 20.0f) ? v : log1pf(expf(v));
                if (resid) v += resid[(size_t)row*ldr + col];
                if (OUTM == 0) ((float*)Cp)[(size_t)row*ldc + col] = v;
                else           ((hbf*)Cp)[(size_t)row*ldc + col] = __float2bfloat16(v);
            }
        }
    }
}

// ---------------- mamba: conv + silu (bf16 in/out) ----------------
__global__ void conv_k(const hbf* __restrict__ xzb, const float* __restrict__ cW,
                       const float* __restrict__ cb, hbf* __restrict__ xcb) {
    int i = blockIdx.x*256 + threadIdx.x;
    int l = i >> 9, d = i & 511;
    float acc = cb[d];
    #pragma unroll
    for (int k = 0; k < 4; k++) {
        int ls = l - 3 + k;
        if (ls >= 0) acc += __bfloat162float(xzb[(size_t)ls*1024 + d]) * cW[d*4 + k];
    }
    float r = acc / (1.0f + __expf(-acc));
    xcb[i] = __float2bfloat16(r);
}

// ---------------- mamba chunked scan (256 chunks x 16 steps) ----------------
__global__ __launch_bounds__(256) void scan1_k(const float* __restrict__ delta,
                        const hbf* __restrict__ xc, const float* __restrict__ proj,
                        const float* __restrict__ Alog,
                        float* __restrict__ P, float* __restrict__ Hl)
{
    int c = blockIdx.x >> 1;
    int d = ((blockIdx.x & 1) << 8) + threadIdx.x;
    float Ac[DSc], pr[DSc], h[DSc];
    #pragma unroll
    for (int s2 = 0; s2 < DSc; s2++) { Ac[s2] = -__expf(Alog[d*DSc+s2]); pr[s2]=1.0f; h[s2]=0.0f; }
    int l0 = c * CLc;
    for (int l = l0; l < l0 + CLc; l++) {
        float dl = delta[(size_t)l*DIc + d];
        float dx = dl * __bfloat162float(xc[(size_t)l*DIc + d]);
        const float* pb = proj + l*32 + 16;
        #pragma unroll
        for (int s2 = 0; s2 < DSc; s2++) {
            float a = __expf(dl * Ac[s2]);
            h[s2] = a*h[s2] + dx*pb[s2];
            pr[s2] *= a;
        }
    }
    #pragma unroll
    for (int s2 = 0; s2 < DSc; s2++) {
        P [(size_t)(c*DSc+s2)*DIc + d] = pr[s2];
        Hl[(size_t)(c*DSc+s2)*DIc + d] = h[s2];
    }
}

// coalesced middle scan: block = 16 consecutive series, LDS tile [256 chunks][16 series]
__global__ __launch_bounds__(256) void scan2t_k(const float* __restrict__ P,
                        const float* __restrict__ Hl, float* __restrict__ Hst) {
    __shared__ float Ps[256][17], Hs[256][17];
    int t = threadIdx.x, sg = blockIdx.x;
    int si = t & 15, cb = t >> 4;
    #pragma unroll
    for (int it = 0; it < 16; it++) {
        int c = it*16 + cb;
        size_t off = (size_t)c*4096 + sg*16 + si;
        Ps[c][si] = P[off];
        Hs[c][si] = Hl[off];
    }
    __syncthreads();
    int si2 = t >> 4, g = t & 15;
    int lane = t & 63;
    // group fold (chunks g*16 .. g*16+15)
    float Pg = 1.0f, Hg = 0.0f;
    #pragma unroll
    for (int j = 0; j < 16; j++) {
        int c = g*16 + j;
        float pc = Ps[c][si2], hc = Hs[c][si2];
        Hg = hc + pc*Hg;
        Pg = pc*Pg;
    }
    // inclusive Hillis-Steele over 16 groups (16-lane windows = fixed series)
    #pragma unroll
    for (int off = 1; off < 16; off <<= 1) {
        float Pp = __shfl(Pg, lane - off);
        float Hp = __shfl(Hg, lane - off);
        if (g >= off) { Hg = Hg + Pg*Hp; Pg = Pg*Pp; }
    }
    float carry = __shfl(Hg, lane - 1);
    if (g == 0) carry = 0.0f;
    // apply: write exclusive prefix per chunk into Hs (own entries only)
    float h = carry;
    #pragma unroll
    for (int j = 0; j < 16; j++) {
        int c = g*16 + j;
        float pc = Ps[c][si2], hc = Hs[c][si2];
        Hs[c][si2] = h;
        h = hc + pc*h;
    }
    __syncthreads();
    #pragma unroll
    for (int it = 0; it < 16; it++) {
        int c = it*16 + cb;
        Hst[(size_t)c*4096 + sg*16 + si] = Hs[c][si];
    }
}

__global__ __launch_bounds__(256) void scan3_k(const float* __restrict__ delta,
                        const hbf* __restrict__ xc, const float* __restrict__ proj,
                        const float* __restrict__ Alog, const float* __restrict__ Hst,
                        const float* __restrict__ Dp, const hbf* __restrict__ xzb,
                        hbf* __restrict__ Y)
{
    int c = blockIdx.x >> 1;
    int d = ((blockIdx.x & 1) << 8) + threadIdx.x;
    float Ac[DSc], h[DSc];
    #pragma unroll
    for (int s2 = 0; s2 < DSc; s2++) {
        Ac[s2] = -__expf(Alog[d*DSc+s2]);
        h[s2]  = Hst[(size_t)(c*DSc+s2)*DIc + d];
    }
    float dpv = Dp[d];
    int l0 = c * CLc;
    for (int l = l0; l < l0 + CLc; l++) {
        float dl = delta[(size_t)l*DIc + d];
        float xv = __bfloat162float(xc[(size_t)l*DIc + d]);
        float dx = dl * xv;
        const float* pb = proj + l*32 + 16;
        float y = 0.0f;
        #pragma unroll
        for (int s2 = 0; s2 < DSc; s2++) {
            float a = __expf(dl * Ac[s2]);
            h[s2] = a*h[s2] + dx*pb[s2];
            y += h[s2] * pb[8+s2];
        }
        float z = __bfloat162float(xzb[(size_t)l*1024 + 512 + d]);
        float sz = z / (1.0f + __expf(-z));
        Y[(size_t)l*DIc + d] = __float2bfloat16((y + dpv*xv) * sz);
    }
}

// ---------------- split-K(8) MFMA flash attention, TQ=128, constant-shift softmax ----------------
// 512 threads / 8 waves: each wave owns 16 q-rows. LDS 36864B -> 4 blocks/CU,
// 32 waves/CU (launch_bounds(512,8) forces VGPR<=64 for full occupancy).
__global__ __launch_bounds__(512, 8) void attn_part_k(const unsigned short* __restrict__ QK,
                       const unsigned short* __restrict__ Vt,
                       OPtrs op, float* __restrict__ lsum)
{
    __shared__ __align__(16) unsigned short QPs[128][72];
    __shared__ __align__(16) unsigned short Ks[64][72];
    __shared__ __align__(16) unsigned short Vs[64][72];
    int t = threadIdx.x, lane = t & 63, w = t >> 6;
    int h = blockIdx.y, q0 = blockIdx.x * 128, skc = blockIdx.z;
    int fm = lane & 15, fq = lane >> 4;

    {
        int qr = t >> 2, qc = (t & 3) * 16;
        const unsigned short* src = &QK[(size_t)(q0+qr)*512 + h*64 + qc];
        *(uint4*)&QPs[qr][qc]     = *(const uint4*)&src[0];
        *(uint4*)&QPs[qr][qc + 8] = *(const uint4*)&src[8];
    }
    __syncthreads();
    bf16x8 qa[2];
    #pragma unroll
    for (int ks = 0; ks < 2; ks++)
        qa[ks] = *(bf16x8*)&QPs[w*16 + fm][ks*32 + fq*8];

    bf16x8 ones;
    #pragma unroll
    for (int j = 0; j < 8; j++) ones[j] = (short)0x3F80;

    f32x4 o[4] = {};
    f32x4 ol = {};
    int sr = t >> 3, sk = (t & 7) * 8;
    const unsigned short* Kb = QK + 256;
    int kt = skc * 512;
    uint4 ka = *(const uint4*)&Kb[(size_t)(kt+sr)*512 + h*64 + sk];
    uint4 va = *(const uint4*)&Vt[(size_t)(h*64+sr)*NL + kt + sk];

    for (int it = 0; it < 8; it++) {
        __syncthreads();
        *(uint4*)&Ks[sr][sk] = ka;
        *(uint4*)&Vs[sr][sk] = va;
        __syncthreads();
        if (it < 7) {
            int kn = kt + 64;
            ka = *(const uint4*)&Kb[(size_t)(kn+sr)*512 + h*64 + sk];
            va = *(const uint4*)&Vt[(size_t)(h*64+sr)*NL + kn + sk];
        }
        f32x4 s[4] = {};
        #pragma unroll
        for (int ks = 0; ks < 2; ks++) {
            #pragma unroll
            for (int nt = 0; nt < 4; nt++) {
                bf16x8 kb = *(bf16x8*)&Ks[nt*16 + fm][ks*32 + fq*8];
                s[nt] = __builtin_amdgcn_mfma_f32_16x16x32_bf16(qa[ks], kb, s[nt], 0, 0, 0);
            }
        }
        #pragma unroll
        for (int nt = 0; nt < 4; nt++)
            #pragma unroll
            for (int i = 0; i < 4; i++) {
                float p = __expf(s[nt][i] - 4.0f);
                *(hbf*)&QPs[w*16 + fq*4 + i][nt*16 + fm] = __float2bfloat16(p);
            }
        #pragma unroll
        for (int ks = 0; ks < 2; ks++) {
            bf16x8 pa = *(bf16x8*)&QPs[w*16 + fm][ks*32 + fq*8];
            #pragma unroll
            for (int nt = 0; nt < 4; nt++) {
                bf16x8 vb = *(bf16x8*)&Vs[nt*16 + fm][ks*32 + fq*8];
                o[nt] = __builtin_amdgcn_mfma_f32_16x16x32_bf16(pa, vb, o[nt], 0, 0, 0);
            }
            ol = __builtin_amdgcn_mfma_f32_16x16x32_bf16(pa, ones, ol, 0, 0, 0);
        }
        kt += 64;
    }
    hbf* Op = op.p[skc];
    #pragma unroll
    for (int i = 0; i < 4; i++) {
        int row = w*16 + fq*4 + i;
        #pragma unroll
        for (int nt = 0; nt < 4; nt++)
            Op[(size_t)(q0 + row)*HH + h*64 + nt*16 + fm] = __float2bfloat16(o[nt][i]);
    }
    if (fm == 0) {
        #pragma unroll
        for (int i = 0; i < 4; i++)
            lsum[(size_t)(skc*4 + h)*NL + q0 + w*16 + fq*4 + i] = ol[i];
    }
}

// exact merge: O = sum_c Oc / sum_c lc
__global__ __launch_bounds__(256) void amerge_k(OPtrs op, const float* __restrict__ lsum,
                                                hbf* __restrict__ aob) {
    int row = blockIdx.x, t = threadIdx.x, h = t >> 6;
    float L = 0.0f, s = 0.0f;
    #pragma unroll
    for (int c = 0; c < 8; c++) {
        L += lsum[(size_t)(c*4 + h)*NL + row];
        s += __bfloat162float(op.p[c][(size_t)row*HH + t]);
    }
    aob[(size_t)row*HH + t] = __float2bfloat16(s / L);
}

// ---------------- layernorm + pooling into 128 partial pools ----------------
__global__ __launch_bounds__(256) void ln_k(const float* __restrict__ X,
                    const float* __restrict__ g, const float* __restrict__ b,
                    float* __restrict__ part) {
    __shared__ float red[4];
    int r = blockIdx.x, t = threadIdx.x;
    float v = X[(size_t)r*HH + t];
    float s = v;
    #pragma unroll
    for (int o = 32; o > 0; o >>= 1) s += __shfl_down(s, o);
    if ((t & 63) == 0) red[t >> 6] = s;
    __syncthreads();
    float mean = (red[0]+red[1]+red[2]+red[3]) * (1.0f/256.0f);
    float dfv = v - mean;
    float s2 = dfv*dfv;
    #pragma unroll
    for (int o = 32; o > 0; o >>= 1) s2 += __shfl_down(s2, o);
    __syncthreads();
    if ((t & 63) == 0) red[t >> 6] = s2;
    __syncthreads();
    float var = (red[0]+red[1]+red[2]+red[3]) * (1.0f/256.0f);
    float y = dfv * rsqrtf(var + 1e-5f) * g[t] + b[t];
    atomicAdd(&part[(size_t)(r & 127)*2048 + (r >> 9)*HH + t], y * (1.0f/512.0f));
}

__global__ void reduce_k(const float* __restrict__ part, float* __restrict__ pooled) {
    int i = blockIdx.x*256 + threadIdx.x;
    float s = 0.0f;
    #pragma unroll 8
    for (int p = 0; p < 128; p++) s += part[(size_t)p*2048 + i];
    pooled[i] = s;
}

// ---------------- heads: wave per output, transposed weights ----------------
__global__ __launch_bounds__(256) void heads_k(const float* __restrict__ pooled,
        const float* __restrict__ hwt,
        const float* cbh, const float* hb, const float* tb, const float* p1b,
        const float* p2b, const float* db, const float* sb, float* __restrict__ out)
{
    int idx = blockIdx.x*4 + (threadIdx.x >> 6);
    int lane = threadIdx.x & 63;
    if (idx >= NOUT) return;
    int b = idx / 1552, j = idx - b*1552;
    const float* bi; int col;
    if (j < 1)         { bi = cbh; col = j;        }
    else if (j < 5)    { bi = hb;  col = j - 1;    }
    else if (j < 8)    { bi = tb;  col = j - 5;    }
    else if (j < 520)  { bi = p1b; col = j - 8;    }
    else if (j < 1032) { bi = p2b; col = j - 520;  }
    else if (j < 1544) { bi = db;  col = j - 1032; }
    else               { bi = sb;  col = j - 1544; }
    const float* pl = pooled + b*HH;
    const float* wr = hwt + (size_t)j*256;
    float s = 0.0f;
    #pragma unroll
    for (int k = lane; k < 256; k += 64) s = fmaf(pl[k], wr[k], s);
    #pragma unroll
    for (int o = 32; o > 0; o >>= 1) s += __shfl_down(s, o);
    if (lane == 0) out[idx] = s + bi[col];
}

// ---------------- launcher ----------------
extern "C" void kernel_launch(void* const* d_in, const int* in_sizes, int n_in,
                              void* d_out, int out_size, void* d_ws, size_t ws_size,
                              hipStream_t stream)
{
    (void)in_sizes; (void)n_in; (void)out_size; (void)ws_size;
    const float* x      = (const float*)d_in[0];
    const int*   ei     = (const int*)  d_in[1];
    const float* W_init = (const float*)d_in[2];
    const float* b_init = (const float*)d_in[3];
    const float* g1W = (const float*)d_in[4];
    const float* g1b = (const float*)d_in[5];
    const float* g2W = (const float*)d_in[6];
    const float* g2b = (const float*)d_in[7];
    const float* inW = (const float*)d_in[8];
    const float* cW  = (const float*)d_in[9];
    const float* cb  = (const float*)d_in[10];
    const float* xpW = (const float*)d_in[11];
    const float* dtW = (const float*)d_in[12];
    const float* dtb = (const float*)d_in[13];
    const float* Alog= (const float*)d_in[14];
    const float* Dp  = (const float*)d_in[15];
    const float* outW= (const float*)d_in[16];
    const float* Wq  = (const float*)d_in[17];
    const float* bq  = (const float*)d_in[18];
    const float* Wk  = (const float*)d_in[19];
    const float* bk  = (const float*)d_in[20];
    const float* Wv  = (const float*)d_in[21];
    const float* bv  = (const float*)d_in[22];
    const float* Wo  = (const float*)d_in[23];
    const float* bo  = (const float*)d_in[24];
    const float* fusW= (const float*)d_in[25];
    const float* fusb= (const float*)d_in[26];
    const float* lng = (const float*)d_in[27];
    const float* lnb = (const float*)d_in[28];
    const float* cwp = (const float*)d_in[29];
    const float* cbp = (const float*)d_in[30];
    const float* hwp = (const float*)d_in[31];
    const float* hbp = (const float*)d_in[32];
    const float* twp = (const float*)d_in[33];
    const float* tbp = (const float*)d_in[34];
    const float* p1w = (const float*)d_in[35];
    const float* p1b = (const float*)d_in[36];
    const float* p2w = (const float*)d_in[37];
    const float* p2b = (const float*)d_in[38];
    const float* dwp = (const float*)d_in[39];
    const float* dbp = (const float*)d_in[40];
    const float* swp = (const float*)d_in[41];
    const float* sbp = (const float*)d_in[42];

    float* fw = (float*)d_ws;
    int* iw = (int*)(fw + O_INT);
    int* indeg = iw;
    int* row_start = iw + 4096;
    int* cursor = iw + 8193;
    int* csr = iw + 12289;
    float* dinv = fw + O_DINV;

    hbf* wt   = (hbf*)(fw + O_WT);
    hbf* xb   = (hbf*)(fw + O_XB);
    hbf* h0b  = (hbf*)(fw + O_H0B);
    hbf* h2b  = (hbf*)(fw + O_H2B);
    hbf* xcb  = (hbf*)(fw + O_XCB);
    hbf* dtab = (hbf*)(fw + O_DTAB);
    hbf* xzb  = (hbf*)(fw + O_XZB);
    hbf* yb   = (hbf*)(fw + O_Y);
    hbf* aob  = (hbf*)(fw + O_Y);
    hbf* catb = (hbf*)(fw + O_CATB);
    hbf* qkB  = (hbf*)(fw + O_QKB);
    hbf* vtB  = (hbf*)(fw + O_VTB);
    float* fused = fw + O_XC;
    float* b768 = fw + O_B768;
    float* part = fw + O_PART;
    float* hwt  = fw + O_HWT;

    float* scanP  = fw + O_MBUF;
    float* scanHl = fw + O_QK;
    float* scanHst= fw + O_HST;
    float* lsum   = fw + O_HST;          // Hst dead after scan3

    OPtrs op;
    op.p[0] = (hbf*)(fw + O_MBUF);
    op.p[1] = (hbf*)(fw + O_MBUF + 524288);
    op.p[2] = (hbf*)(fw + O_DELTA);
    op.p[3] = (hbf*)(fw + O_DELTA + 524288);
    op.p[4] = (hbf*)(fw + O_DELTA + 1048576);
    op.p[5] = (hbf*)(fw + O_DELTA + 1572864);
    op.p[6] = (hbf*)(fw + O_XZB);
    op.p[7] = (hbf*)(fw + O_XZB + 524288);

    hbf* WtInit  = wt + 0;
    hbf* WtG1    = wt + 8192;
    hbf* WtG2    = wt + 73728;
    hbf* WtXp    = wt + 139264;
    hbf* WtDt    = wt + 155648;
    hbf* WtOut   = wt + 172032;
    hbf* WtInQKV = wt + 303104;
    hbf* WtO     = wt + 761856;
    hbf* WtFus   = wt + 827392;

    WSrc wsrc;
    wsrc.p[0]=W_init; wsrc.p[1]=g1W; wsrc.p[2]=g2W; wsrc.p[3]=xpW; wsrc.p[4]=dtW;
    wsrc.p[5]=outW; wsrc.p[6]=inW; wsrc.p[7]=Wq; wsrc.p[8]=Wk; wsrc.p[9]=Wv;
    wsrc.p[10]=Wo; wsrc.p[11]=fusW;
    HSrc hsrc;
    hsrc.p[0]=cwp; hsrc.p[1]=hwp; hsrc.p[2]=twp; hsrc.p[3]=p1w;
    hsrc.p[4]=p2w; hsrc.p[5]=dwp; hsrc.p[6]=swp;
    prep_k<<<(PR_H+255)/256,256,0,stream>>>(wsrc, wt, x, xb, bq, bk, bv, b768,
                                            part, indeg, hsrc, hwt);

    // graph prep
    count_k<<<256,256,0,stream>>>(ei, indeg);
    prefix_k<<<1,1024,0,stream>>>(indeg, row_start, cursor, dinv);
    scatter_k<<<256,256,0,stream>>>(ei, cursor, csr);

    // h0 = relu(x @ W_init + b_init) -> bf16
    mg_k<1,1><<<dim3(64,4),512,0,stream>>>((const unsigned short*)xb, (const unsigned short*)WtInit,
        b_init, h0b, 256, nullptr, nullptr, nullptr, 0, NL, 32, 256);
    // gcn1
    mg_k<0,0><<<dim3(64,4),512,0,stream>>>((const unsigned short*)h0b, (const unsigned short*)WtG1,
        nullptr, fw+O_MBUF, 256, nullptr, nullptr, nullptr, 0, NL, 256, 256);
    gather_k<0><<<4096,256,0,stream>>>(fw+O_MBUF, csr, row_start, dinv, g1b, nullptr, h0b, nullptr);
    // gcn2 (fp32 h2 + bf16 h2b + catb cols 0..255)
    mg_k<0,0><<<dim3(64,4),512,0,stream>>>((const unsigned short*)h0b, (const unsigned short*)WtG2,
        nullptr, fw+O_MBUF, 256, nullptr, nullptr, nullptr, 0, NL, 256, 256);
    gather_k<1><<<4096,256,0,stream>>>(fw+O_MBUF, csr, row_start, dinv, g2b, fw+O_H2, h2b, catb);

    // fused in_proj + QKV (N=1792): xzb | qkB (Q scaled) | vtB (transposed)
    mg_k<0,5><<<dim3(64,28),512,0,stream>>>((const unsigned short*)h2b, (const unsigned short*)WtInQKV,
        b768, xzb, 1024, qkB, vtB, nullptr, 0, NL, 256, 1792);

    // mamba
    conv_k<<<8192,256,0,stream>>>(xzb, cW, cb, xcb);
    mg_k<0,4><<<dim3(64,1),512,0,stream>>>((const unsigned short*)xcb, (const unsigned short*)WtXp,
        nullptr, fw+O_PROJ, 32, dtab, nullptr, nullptr, 0, NL, 512, 32);
    mg_k<2,0><<<dim3(64,8),512,0,stream>>>((const unsigned short*)dtab, (const unsigned short*)WtDt,
        dtb, fw+O_DELTA, 512, nullptr, nullptr, nullptr, 0, NL, 32, 512);
    scan1_k<<<512,256,0,stream>>>(fw+O_DELTA, xcb, fw+O_PROJ, Alog, scanP, scanHl);
    scan2t_k<<<256,256,0,stream>>>(scanP, scanHl, scanHst);
    scan3_k<<<512,256,0,stream>>>(fw+O_DELTA, xcb, fw+O_PROJ, Alog, scanHst, Dp, xzb, yb);
    mg_k<0,1><<<dim3(64,4),512,0,stream>>>((const unsigned short*)yb, (const unsigned short*)WtOut,
        nullptr, catb + 256, 768, nullptr, nullptr, nullptr, 0, NL, 512, 256);

    // attention
    attn_part_k<<<dim3(32,4,8),512,0,stream>>>((const unsigned short*)qkB,
        (const unsigned short*)vtB, op, lsum);
    amerge_k<<<4096,256,0,stream>>>(op, lsum, aob);
    mg_k<0,1><<<dim3(64,4),512,0,stream>>>((const unsigned short*)aob, (const unsigned short*)WtO,
        bo, catb + 512, 768, nullptr, nullptr, nullptr, 0, NL, 256, 256);

    // fuse + residual + LN(+partial pool) + reduce + heads
    mg_k<1,0><<<dim3(64,4),512,0,stream>>>((const unsigned short*)catb, (const unsigned short*)WtFus,
        fusb, fused, 256, nullptr, nullptr, fw+O_H2, 256, NL, 768, 256);
    ln_k<<<4096,256,0,stream>>>(fused, lng, lnb, part);
    reduce_k<<<8,256,0,stream>>>(part, fw+O_POOL);
    heads_k<<<(NOUT+3)/4,256,0,stream>>>(fw+O_POOL, hwt, cbp,hbp,tbp,p1b,p2b,dbp,sbp,
                                         (float*)d_out);
}